// Round 1
// baseline (4299.089 us; speedup 1.0000x reference)
//
#include <hip/hip_runtime.h>
#include <math.h>

#define B 8
#define N 2048
#define D 1024

#define TM 64
#define TN 64
#define TK 16

// ---------------------------------------------------------------------------
// NT GEMM: C[m,n] = sum_k A[m,k] * Bm[n,k]   (both row-major, contract last dim)
// lda = K, ldb = K, ldc = Nc. Batched via blockIdx.z with element strides.
// 64x64 tile, 256 threads, 4x4 register micro-tile.
// ---------------------------------------------------------------------------
__global__ __launch_bounds__(256) void gemm_nt(
    const float* __restrict__ A, const float* __restrict__ Bm, float* __restrict__ C,
    int M, int Nc, int K, size_t sA, size_t sB, size_t sC)
{
    __shared__ float As[TK][TM + 1];
    __shared__ float Bs[TK][TN + 1];
    const float* Ab = A + (size_t)blockIdx.z * sA;
    const float* Bb = Bm + (size_t)blockIdx.z * sB;
    float* Cb = C + (size_t)blockIdx.z * sC;
    const int m0 = blockIdx.y * TM, n0 = blockIdx.x * TN;
    const int lin = threadIdx.x;
    const int tx = lin & 15, ty = lin >> 4;

    float acc[4][4] = {};

    for (int k0 = 0; k0 < K; k0 += TK) {
#pragma unroll
        for (int q = 0; q < 4; ++q) {
            int e = lin + q * 256;          // 0..1023 over 64 rows x 16 k
            int m = e >> 4, k = e & 15;
            As[k][m] = Ab[(size_t)(m0 + m) * K + k0 + k];
            Bs[k][m] = Bb[(size_t)(n0 + m) * K + k0 + k];
        }
        __syncthreads();
#pragma unroll
        for (int k = 0; k < TK; ++k) {
            float a[4], b[4];
#pragma unroll
            for (int i = 0; i < 4; ++i) a[i] = As[k][ty + 16 * i];
#pragma unroll
            for (int j = 0; j < 4; ++j) b[j] = Bs[k][tx + 16 * j];
#pragma unroll
            for (int i = 0; i < 4; ++i)
#pragma unroll
                for (int j = 0; j < 4; ++j) acc[i][j] += a[i] * b[j];
        }
        __syncthreads();
    }

#pragma unroll
    for (int i = 0; i < 4; ++i) {
        int m = m0 + ty + 16 * i;
#pragma unroll
        for (int j = 0; j < 4; ++j) {
            int n = n0 + tx + 16 * j;
            Cb[(size_t)m * Nc + n] = acc[i][j];
        }
    }
}

// ---------------------------------------------------------------------------
// Column softmax over the QUERY axis: for each (b, m) normalize S[b, :, m].
// S is [B][N(n)][N(m)] row-major. One block = 64 columns (m) x 4 n-slices.
// Reads/writes coalesced across m. In-place: S becomes alpha.
// ---------------------------------------------------------------------------
__global__ __launch_bounds__(256) void col_softmax(float* __restrict__ S)
{
    const int b = blockIdx.x / (N / 64);
    const int mbase = (blockIdx.x % (N / 64)) * 64;
    const int t = threadIdx.x;
    const int mloc = t & 63;
    const int slice = t >> 6;             // 0..3
    const int m = mbase + mloc;
    float* Sb = S + (size_t)b * N * N;
    const int n_lo = slice * (N / 4), n_hi = n_lo + (N / 4);

    __shared__ float red[4][64];

    float mx = -INFINITY;
    for (int n = n_lo; n < n_hi; ++n)
        mx = fmaxf(mx, Sb[(size_t)n * N + m]);
    red[slice][mloc] = mx;
    __syncthreads();
    mx = fmaxf(fmaxf(red[0][mloc], red[1][mloc]), fmaxf(red[2][mloc], red[3][mloc]));
    __syncthreads();

    float s = 0.0f;
    for (int n = n_lo; n < n_hi; ++n)
        s += __expf(Sb[(size_t)n * N + m] - mx);
    red[slice][mloc] = s;
    __syncthreads();
    float den = red[0][mloc] + red[1][mloc] + red[2][mloc] + red[3][mloc];
    float inv = 1.0f / den;

    for (int n = n_lo; n < n_hi; ++n) {
        size_t idx = (size_t)n * N + m;
        Sb[idx] = __expf(Sb[idx] - mx) * inv;
    }
}

// ---------------------------------------------------------------------------
// NN GEMM with fused epilogue: C[n,v] = sum_m Alpha[n,m] * V[m,v];
// writes Out = C and Feat = C + Text. Per-batch via blockIdx.z.
// ---------------------------------------------------------------------------
__global__ __launch_bounds__(256) void gemm_nn_pv(
    const float* __restrict__ Alpha, const float* __restrict__ Vm,
    const float* __restrict__ Text, float* __restrict__ Out, float* __restrict__ Feat)
{
    __shared__ float As[TK][TM + 1];
    __shared__ float Bs[TK][TN + 1];
    const size_t bz = blockIdx.z;
    const float* Ab = Alpha + bz * (size_t)N * N;
    const float* Bb = Vm + bz * (size_t)N * D;
    const float* Tb = Text + bz * (size_t)N * D;
    float* Ob = Out + bz * (size_t)N * D;
    float* Fb = Feat + bz * (size_t)N * D;
    const int m0 = blockIdx.y * TM, n0 = blockIdx.x * TN;
    const int lin = threadIdx.x;
    const int tx = lin & 15, ty = lin >> 4;

    float acc[4][4] = {};

    for (int k0 = 0; k0 < N; k0 += TK) {
#pragma unroll
        for (int q = 0; q < 4; ++q) {
            int e = lin + q * 256;
            int m = e >> 4, k = e & 15;           // A tile: 64 rows x 16 k
            As[k][m] = Ab[(size_t)(m0 + m) * N + k0 + k];
            int kk = e >> 6, n = e & 63;          // B tile: 16 k x 64 cols (coalesced)
            Bs[kk][n] = Bb[(size_t)(k0 + kk) * D + n0 + n];
        }
        __syncthreads();
#pragma unroll
        for (int k = 0; k < TK; ++k) {
            float a[4], b[4];
#pragma unroll
            for (int i = 0; i < 4; ++i) a[i] = As[k][ty + 16 * i];
#pragma unroll
            for (int j = 0; j < 4; ++j) b[j] = Bs[k][tx + 16 * j];
#pragma unroll
            for (int i = 0; i < 4; ++i)
#pragma unroll
                for (int j = 0; j < 4; ++j) acc[i][j] += a[i] * b[j];
        }
        __syncthreads();
    }

#pragma unroll
    for (int i = 0; i < 4; ++i) {
        int n = m0 + ty + 16 * i;                 // output row (query index)
#pragma unroll
        for (int j = 0; j < 4; ++j) {
            int v = n0 + tx + 16 * j;             // output col (value dim)
            size_t idx = (size_t)n * D + v;
            float c = acc[i][j];
            Ob[idx] = c;
            Fb[idx] = c + Tb[idx];
        }
    }
}

// ---------------------------------------------------------------------------
extern "C" void kernel_launch(void* const* d_in, const int* in_sizes, int n_in,
                              void* d_out, int out_size, void* d_ws, size_t ws_size,
                              hipStream_t stream)
{
    const float* img  = (const float*)d_in[0];
    const float* text = (const float*)d_in[1];
    const float* Wq   = (const float*)d_in[2];
    const float* Wk   = (const float*)d_in[3];
    const float* Wv   = (const float*)d_in[4];

    float* out  = (float*)d_out;                       // [B*N*D]
    float* feat = out + (size_t)B * N * D;             // [B*N*D]

    // Scratch plan (minimize ws usage): Q and K live in d_out (dead until the
    // final kernel overwrites it); V and S live in ws (201 MB).
    float* Q  = out;                                   // 67 MB
    float* Km = feat;                                  // 67 MB
    float* Vm = (float*)d_ws;                          // 67 MB
    float* S  = Vm + (size_t)B * N * D;                // 134 MB

    dim3 blk(256);

    // Projections: y = x @ W^T  (NT GEMM), batch folded into M.
    gemm_nt<<<dim3(D / TN, (B * N) / TM, 1), blk, 0, stream>>>(img,  Wq, Q,  B * N, D, D, 0, 0, 0);
    gemm_nt<<<dim3(D / TN, (B * N) / TM, 1), blk, 0, stream>>>(text, Wk, Km, B * N, D, D, 0, 0, 0);
    gemm_nt<<<dim3(D / TN, (B * N) / TM, 1), blk, 0, stream>>>(text, Wv, Vm, B * N, D, D, 0, 0, 0);

    // S[b] = Q[b] @ K[b]^T  (NT, batched)
    gemm_nt<<<dim3(N / TN, N / TM, B), blk, 0, stream>>>(Q, Km, S, N, N, D,
                                                         (size_t)N * D, (size_t)N * D, (size_t)N * N);

    // softmax over query axis (column-wise in S[n][m]) — in place
    col_softmax<<<dim3(B * N / 64), blk, 0, stream>>>(S);

    // out = alpha @ V ; feature = out + text  (NN, batched, fused epilogue)
    gemm_nn_pv<<<dim3(D / TN, N / TM, B), blk, 0, stream>>>(S, Vm, text, out, feat);
}

// Round 2
// 1126.053 us; speedup vs baseline: 3.8178x; 3.8178x over previous
//
#include <hip/hip_runtime.h>
#include <math.h>

#define B 8
#define N 2048
#define D 1024

#define BM 128
#define BN 128
#define BK 32

typedef __bf16 bf16;
typedef __bf16 bf16x8 __attribute__((ext_vector_type(8)));
typedef __bf16 bf16x4 __attribute__((ext_vector_type(4)));
typedef float f32x4 __attribute__((ext_vector_type(4)));

__device__ __forceinline__ void load_lds16(const void* g, void* l) {
    __builtin_amdgcn_global_load_lds((const __attribute__((address_space(1))) void*)g,
                                     (__attribute__((address_space(3))) void*)l, 16, 0, 0);
}

// ---------------------------------------------------------------------------
// Split fp32 x into bf16 hi + lo residual (hi = RN(x), lo = RN(x - hi)).
// ---------------------------------------------------------------------------
__global__ __launch_bounds__(256) void split_fp32(const float* __restrict__ x,
                                                  bf16* __restrict__ h,
                                                  bf16* __restrict__ l, long n)
{
    long i = ((long)blockIdx.x * 256 + threadIdx.x) * 4;
    if (i >= n) return;
    float4 v = *(const float4*)(x + i);
    float vs[4] = {v.x, v.y, v.z, v.w};
    bf16x4 hh, ll;
#pragma unroll
    for (int t = 0; t < 4; ++t) {
        bf16 hv = (bf16)vs[t];
        hh[t] = hv;
        ll[t] = (bf16)(vs[t] - (float)hv);
    }
    *(bf16x4*)(h + i) = hh;
    *(bf16x4*)(l + i) = ll;
}

// ---------------------------------------------------------------------------
// Unified NT MFMA GEMM: C[i,j] = sum_k A[i,k] * Bm[j,k]  (both K-contracted
// row-major). 128x128 tile, BK=32, 256 threads = 2x2 waves of 4x4
// mfma_f32_16x16x32_bf16. TERMS: 1 = hi*hi only; 3 = split-bf16 3-term.
// AF32: A operand is fp32 in global, converted to bf16-hi during LDS staging.
// EPI: 0 = write bf16 hi (+lo if Clo) ; 1 = write fp32 C ; 2 = PV epilogue
// (Out = C, Feat = C + Text, both fp32).
// ---------------------------------------------------------------------------
template<int TERMS, int EPI, bool AF32>
__global__ __launch_bounds__(256) void gemm_nt_mfma(
    const void* __restrict__ Ah_g_, const bf16* __restrict__ Al_g,
    const bf16* __restrict__ Bh_g, const bf16* __restrict__ Bl_g,
    bf16* __restrict__ Chi, bf16* __restrict__ Clo,
    float* __restrict__ Cf, const float* __restrict__ Text,
    float* __restrict__ Feat,
    int Mdim, int Ncdim, int Kdim, long sA, long sB, long sC)
{
    __shared__ bf16 Ah[BM][BK];
    __shared__ bf16 Bh[BN][BK];
    __shared__ bf16 Al[BM][BK];
    __shared__ bf16 Bl[BN][BK];

    const int tid = threadIdx.x;
    const int lane = tid & 63;
    const int wv = tid >> 6;
    const int wr = (wv >> 1) * 64;    // wave row offset in tile
    const int wc = (wv & 1) * 64;     // wave col offset in tile
    const int mfrag = lane & 15;
    const int quad = lane >> 4;

    const long z = blockIdx.z;
    const int row0 = blockIdx.y * BM;
    const int col0 = blockIdx.x * BN;

    const bf16* Abh = AF32 ? nullptr : ((const bf16*)Ah_g_) + z * sA;
    const float* Af  = AF32 ? ((const float*)Ah_g_) + z * sA : nullptr;
    const bf16* Abl = (TERMS == 3) ? (Al_g + z * sA) : nullptr;
    const bf16* Bbh = Bh_g + z * sB;
    const bf16* Bbl = (TERMS == 3) ? (Bl_g + z * sB) : nullptr;

    f32x4 acc[4][4] = {};

    for (int k0 = 0; k0 < Kdim; k0 += BK) {
        // ---- stage A tile ----
        if constexpr (AF32) {
#pragma unroll
            for (int q = 0; q < 2; ++q) {
                int c = q * 256 + tid;
                int row = c >> 2, kp = (c & 3) * 8;
                const float* gp = Af + (long)(row0 + row) * Kdim + k0 + kp;
                float4 f0 = *(const float4*)gp;
                float4 f1 = *(const float4*)(gp + 4);
                bf16x8 v;
                v[0] = (bf16)f0.x; v[1] = (bf16)f0.y; v[2] = (bf16)f0.z; v[3] = (bf16)f0.w;
                v[4] = (bf16)f1.x; v[5] = (bf16)f1.y; v[6] = (bf16)f1.z; v[7] = (bf16)f1.w;
                *(bf16x8*)&Ah[row][kp] = v;
            }
        } else {
#pragma unroll
            for (int q = 0; q < 2; ++q) {
                int c = q * 256 + tid;
                int row = c >> 2, kp = (c & 3) * 8;
                load_lds16(Abh + (long)(row0 + row) * Kdim + k0 + kp, &Ah[row][kp]);
                if constexpr (TERMS == 3)
                    load_lds16(Abl + (long)(row0 + row) * Kdim + k0 + kp, &Al[row][kp]);
            }
        }
        // ---- stage B tile ----
#pragma unroll
        for (int q = 0; q < 2; ++q) {
            int c = q * 256 + tid;
            int row = c >> 2, kp = (c & 3) * 8;
            load_lds16(Bbh + (long)(col0 + row) * Kdim + k0 + kp, &Bh[row][kp]);
            if constexpr (TERMS == 3)
                load_lds16(Bbl + (long)(col0 + row) * Kdim + k0 + kp, &Bl[row][kp]);
        }
        __syncthreads();

        bf16x8 a_h[4], b_h[4], a_l[4], b_l[4];
#pragma unroll
        for (int i = 0; i < 4; ++i) {
            a_h[i] = *(const bf16x8*)&Ah[wr + i * 16 + mfrag][quad * 8];
            b_h[i] = *(const bf16x8*)&Bh[wc + i * 16 + mfrag][quad * 8];
            if constexpr (TERMS == 3) {
                a_l[i] = *(const bf16x8*)&Al[wr + i * 16 + mfrag][quad * 8];
                b_l[i] = *(const bf16x8*)&Bl[wc + i * 16 + mfrag][quad * 8];
            }
        }
#pragma unroll
        for (int i = 0; i < 4; ++i)
#pragma unroll
            for (int j = 0; j < 4; ++j) {
                acc[i][j] = __builtin_amdgcn_mfma_f32_16x16x32_bf16(a_h[i], b_h[j], acc[i][j], 0, 0, 0);
                if constexpr (TERMS == 3) {
                    acc[i][j] = __builtin_amdgcn_mfma_f32_16x16x32_bf16(a_h[i], b_l[j], acc[i][j], 0, 0, 0);
                    acc[i][j] = __builtin_amdgcn_mfma_f32_16x16x32_bf16(a_l[i], b_h[j], acc[i][j], 0, 0, 0);
                }
            }
        __syncthreads();
    }

    // ---- epilogue ---- C/D layout: col = lane&15, row = quad*4 + reg
    const long cbase = z * sC;
    const bool wlo = (Clo != nullptr);
#pragma unroll
    for (int i = 0; i < 4; ++i) {
#pragma unroll
        for (int r = 0; r < 4; ++r) {
            int row = row0 + wr + i * 16 + quad * 4 + r;
#pragma unroll
            for (int j = 0; j < 4; ++j) {
                int col = col0 + wc + j * 16 + mfrag;
                long idx = cbase + (long)row * Ncdim + col;
                float v = acc[i][j][r];
                if constexpr (EPI == 0) {
                    bf16 h = (bf16)v;
                    Chi[idx] = h;
                    if (wlo) Clo[idx] = (bf16)(v - (float)h);
                } else if constexpr (EPI == 1) {
                    Cf[idx] = v;
                } else {
                    Cf[idx] = v;
                    Feat[idx] = v + Text[idx];
                }
            }
        }
    }
}

// ---------------------------------------------------------------------------
// Column softmax over the QUERY axis (in place, fp32): for each (b, m)
// normalize S[b, :, m]. Identical to the round-1 verified kernel.
// ---------------------------------------------------------------------------
__global__ __launch_bounds__(256) void col_softmax(float* __restrict__ S)
{
    const int b = blockIdx.x / (N / 64);
    const int mbase = (blockIdx.x % (N / 64)) * 64;
    const int t = threadIdx.x;
    const int mloc = t & 63;
    const int slice = t >> 6;
    const int m = mbase + mloc;
    float* Sb = S + (size_t)b * N * N;
    const int n_lo = slice * (N / 4), n_hi = n_lo + (N / 4);

    __shared__ float red[4][64];

    float mx = -INFINITY;
    for (int n = n_lo; n < n_hi; ++n)
        mx = fmaxf(mx, Sb[(size_t)n * N + m]);
    red[slice][mloc] = mx;
    __syncthreads();
    mx = fmaxf(fmaxf(red[0][mloc], red[1][mloc]), fmaxf(red[2][mloc], red[3][mloc]));
    __syncthreads();

    float s = 0.0f;
    for (int n = n_lo; n < n_hi; ++n)
        s += __expf(Sb[(size_t)n * N + m] - mx);
    red[slice][mloc] = s;
    __syncthreads();
    float den = red[0][mloc] + red[1][mloc] + red[2][mloc] + red[3][mloc];
    float inv = 1.0f / den;

    for (int n = n_lo; n < n_hi; ++n) {
        size_t idx = (size_t)n * N + m;
        Sb[idx] = __expf(Sb[idx] - mx) * inv;
    }
}

// ---------------------------------------------------------------------------
extern "C" void kernel_launch(void* const* d_in, const int* in_sizes, int n_in,
                              void* d_out, int out_size, void* d_ws, size_t ws_size,
                              hipStream_t stream)
{
    const float* img  = (const float*)d_in[0];
    const float* text = (const float*)d_in[1];
    const float* Wq   = (const float*)d_in[2];
    const float* Wk   = (const float*)d_in[3];
    const float* Wv   = (const float*)d_in[4];

    float* out  = (float*)d_out;
    float* feat = out + (long)B * N * D;

    const long E  = (long)B * N * D;   // 16.78M elems
    const long W2 = (long)D * D;       // 1.05M elems
    const long EN = (long)B * N * N;   // 33.55M elems

    // ws layout (peak 180.3 MB; 201.3 MB proven in round 1):
    //   [0 .. 8E bytes)        img_h/img_l/text_h/text_l  -> later S fp32 (EN*4 = 8E bytes)
    //   [8E .. 8E+12W2*2)      Wq/Wk/Wv hi+lo
    //   [.. +E*2)              VT_h
    // d_out: Q_h Q_l K_h K_l (4E bf16 = exactly out bytes), dead before PV writes.
    char* ws = (char*)d_ws;
    bf16* img_h  = (bf16*)ws;
    bf16* img_l  = img_h + E;
    bf16* text_h = img_l + E;
    bf16* text_l = text_h + E;
    float* S     = (float*)ws;             // aliases img/text splits (dead by then)
    bf16* Wq_h = (bf16*)(ws + (size_t)EN * 4);
    bf16* Wq_l = Wq_h + W2;
    bf16* Wk_h = Wq_l + W2;
    bf16* Wk_l = Wk_h + W2;
    bf16* Wv_h = Wk_l + W2;
    bf16* Wv_l = Wv_h + W2;
    bf16* VT_h = Wv_l + W2;

    bf16* Q_h = (bf16*)d_out;
    bf16* Q_l = Q_h + E;
    bf16* K_h = Q_l + E;
    bf16* K_l = K_h + E;

    dim3 blk(256);

    // 1. split inputs to bf16 hi/lo
    split_fp32<<<E / 1024, blk, 0, stream>>>(img,  img_h,  img_l,  E);
    split_fp32<<<E / 1024, blk, 0, stream>>>(text, text_h, text_l, E);
    split_fp32<<<W2 / 1024, blk, 0, stream>>>(Wq, Wq_h, Wq_l, W2);
    split_fp32<<<W2 / 1024, blk, 0, stream>>>(Wk, Wk_h, Wk_l, W2);
    split_fp32<<<W2 / 1024, blk, 0, stream>>>(Wv, Wv_h, Wv_l, W2);

    // 2. Q = img @ Wq^T (split out), K = text @ Wk^T (split out), batch folded
    gemm_nt_mfma<3, 0, false><<<dim3(D / BN, (B * N) / BM, 1), blk, 0, stream>>>(
        img_h, img_l, Wq_h, Wq_l, Q_h, Q_l, nullptr, nullptr, nullptr,
        B * N, D, D, 0, 0, 0);
    gemm_nt_mfma<3, 0, false><<<dim3(D / BN, (B * N) / BM, 1), blk, 0, stream>>>(
        text_h, text_l, Wk_h, Wk_l, K_h, K_l, nullptr, nullptr, nullptr,
        B * N, D, D, 0, 0, 0);

    // 3. VT[b][v][m] = sum_d Wv[v,d] * text[b,m,d]  (1-term, hi only)
    gemm_nt_mfma<1, 0, false><<<dim3(N / BN, D / BM, B), blk, 0, stream>>>(
        Wv_h, nullptr, text_h, nullptr, VT_h, nullptr, nullptr, nullptr, nullptr,
        D, N, D, 0, (long)N * D, (long)D * N);

    // 4. S[b] = Q[b] @ K[b]^T (3-term split, fp32 out) — overwrites img/text splits
    gemm_nt_mfma<3, 1, false><<<dim3(N / BN, N / BM, B), blk, 0, stream>>>(
        Q_h, Q_l, K_h, K_l, nullptr, nullptr, S, nullptr, nullptr,
        N, N, D, (long)N * D, (long)N * D, (long)N * N);

    // 5. softmax over query axis, in place (S -> alpha, fp32)
    col_softmax<<<dim3(B * N / 64), blk, 0, stream>>>(S);

    // 6. out[b][n][v] = sum_m alpha[b][n][m] * VT[b][v][m]; feat = out + text
    gemm_nt_mfma<1, 2, true><<<dim3(D / BN, N / BM, B), blk, 0, stream>>>(
        S, nullptr, VT_h, nullptr, nullptr, nullptr, out, text, feat,
        N, D, N, (long)N * N, (long)D * N, (long)N * D);
}